// Round 3
// baseline (591.986 us; speedup 1.0000x reference)
//
#include <hip/hip_runtime.h>

// ---------------------------------------------------------------------------
// CrossAttention on MI355X (gfx950) — round 5.
//
// v4 post-mortem: fused kernel moved 1.03 GB (compulsory ~300 MB) at 2.76 TB/s,
// queue-limited (MfmaUtil 4%, occ 20%). Excess = 8x broadcast stores thrashing
// L2 + 1.2 GB weight re-reads + cross-XCD half-line writes.
//
// v5:
//  * fused kernel writes unique Y ONCE to ws; ca_bcast streams the 8x
//    replication with full-line contiguous stores (151 MB @ streaming BW).
//  * LDS 70.7 -> 52.2 KB (K/V gemm split, no yreg, 2-pass ybuf) => 3 blocks/CU.
//  * XCD swizzle: (bk, nh=0/1) pair on same XCD (half-line write merge,
//    hot WKV per-XCD).
//
// ws: [WCQ 512x256 bf16][WKV 512x256][WOET 256x256][Yws nk*16384 f32]
// ---------------------------------------------------------------------------

typedef unsigned short u16;
typedef u16  u16x8 __attribute__((ext_vector_type(8)));
typedef u16  u16x4 __attribute__((ext_vector_type(4)));
typedef __bf16 bf16x8 __attribute__((ext_vector_type(8)));
typedef float f32x4 __attribute__((ext_vector_type(4)));

#define XS  264   // LDS stride (u16) for 256-wide bf16 tiles
#define YSF 36    // LDS stride (f32) for 128x32 f32 transpose buffer

__device__ __forceinline__ u16 f2bf(float f) {
  union { float f; unsigned u; } t; t.f = f;
  unsigned r = t.u + 0x7FFF + ((t.u >> 16) & 1);
  return (u16)(r >> 16);
}
__device__ __forceinline__ float bf2f(u16 x) {
  union { unsigned u; float f; } t; t.u = ((unsigned)x) << 16;
  return t.f;
}

// D[o][n] = sum_c WT[o][c]*X[n][c]; rows = MT*4*16, N = 32, K = 256.
// WT from global (L2-resident weights), X from LDS [n][XS].
template <int MT>
__device__ __forceinline__ void gemm_run(const u16* __restrict__ WT,
                                         const u16* __restrict__ X,
                                         int wave, int col, int quad,
                                         f32x4 (&acc)[MT][2]) {
#pragma unroll
  for (int mt = 0; mt < MT; ++mt)
#pragma unroll
    for (int nt = 0; nt < 2; ++nt)
      acc[mt][nt] = (f32x4)(0.0f);
  for (int ks = 0; ks < 8; ++ks) {
    bf16x8 bfr[2];
#pragma unroll
    for (int nt = 0; nt < 2; ++nt)
      bfr[nt] = __builtin_bit_cast(
          bf16x8, *(const u16x8*)&X[(nt * 16 + col) * XS + ks * 32 + quad * 8]);
#pragma unroll
    for (int mt = 0; mt < MT; ++mt) {
      const int m = (wave * MT + mt) * 16 + col;
      bf16x8 afr = __builtin_bit_cast(
          bf16x8, *(const u16x8*)&WT[m * 256 + ks * 32 + quad * 8]);
#pragma unroll
      for (int nt = 0; nt < 2; ++nt)
        acc[mt][nt] = __builtin_amdgcn_mfma_f32_16x16x32_bf16(
            afr, bfr[nt], acc[mt][nt], 0, 0, 0);
    }
  }
}

// ---------------------------------------------------------------------------
// Setup: WCQ rows 0..255 = (Wv_ego @ W_out_other)^T, rows 256..511 = Wq_ego^T
// ---------------------------------------------------------------------------
__global__ void ca_setup_fuse(const float* __restrict__ Wqkv_e,
                              const float* __restrict__ Woo,
                              u16* __restrict__ WCQ) {
  const int c = blockIdx.x, o = threadIdx.x;
  __shared__ float wv[256];
  wv[o] = Wqkv_e[c * 768 + 512 + o];
  __syncthreads();
  float s = 0.f;
#pragma unroll 8
  for (int j = 0; j < 256; ++j) s += wv[j] * Woo[j * 256 + o];
  WCQ[o * 256 + c] = f2bf(s);
}

// Tiled 64x64 LDS transpose for the three weight sections (coalesced both
// sides; old version did 1024*256 scalar 3KB-strided loads).
__global__ void ca_setup_trans(const float* __restrict__ Wqkv_e,
                               const float* __restrict__ Wqkv_o,
                               const float* __restrict__ Woe,
                               u16* __restrict__ WCQ, u16* __restrict__ WKV,
                               u16* __restrict__ WOET) {
  const int bid = blockIdx.x;               // 64 blocks: job(2b)|ot(2b)|ct(2b)
  const int job = bid >> 4, ot = (bid >> 2) & 3, ct = bid & 3;
  const float* src; int stride, coff; u16* dst;
  if (job == 0)      { src = Wqkv_e; stride = 768; coff = 0;   dst = WCQ + 65536; }
  else if (job == 1) { src = Wqkv_o; stride = 768; coff = 256; dst = WKV; }
  else if (job == 2) { src = Wqkv_o; stride = 768; coff = 512; dst = WKV + 65536; }
  else               { src = Woe;    stride = 256; coff = 0;   dst = WOET; }
  __shared__ float tile[64][65];
  const int t = threadIdx.x, tc = t & 15, tr = t >> 4;   // tr in [0,16)
#pragma unroll
  for (int j = 0; j < 4; ++j) {
    const int cl = tr + j * 16;                          // local src row
    const f32x4 v =
        *(const f32x4*)&src[(ct * 64 + cl) * stride + coff + ot * 64 + tc * 4];
#pragma unroll
    for (int e = 0; e < 4; ++e) tile[cl][tc * 4 + e] = v[e];
  }
  __syncthreads();
#pragma unroll
  for (int j = 0; j < 4; ++j) {
    const int ol = tr + j * 16;                          // local dst row (o)
    u16x4 p;
#pragma unroll
    for (int e = 0; e < 4; ++e) p[e] = f2bf(tile[tc * 4 + e][ol]);
    *(u16x4*)&dst[(ot * 64 + ol) * 256 + ct * 64 + tc * 4] = p;
  }
}

// ---------------------------------------------------------------------------
// Tile staging: 32 pixels x 256 ch, f32 [c][64] global -> bf16 [n][c] LDS.
// ---------------------------------------------------------------------------
__device__ __forceinline__ void tile_load(const float* __restrict__ src, int t,
                                          f32x4 (&g)[2][4]) {
#pragma unroll
  for (int it = 0; it < 2; ++it) {
    const int id = t + it * 256;
    const int n0 = (id & 7) * 4, c0 = (id >> 3) * 4;
#pragma unroll
    for (int i = 0; i < 4; ++i)
      g[it][i] = *(const f32x4*)&src[(c0 + i) * 64 + n0];
  }
}
__device__ __forceinline__ void tile_write(const f32x4 (&g)[2][4],
                                           u16* __restrict__ xbuf, int t) {
#pragma unroll
  for (int it = 0; it < 2; ++it) {
    const int id = t + it * 256;
    const int n0 = (id & 7) * 4, c0 = (id >> 3) * 4;
#pragma unroll
    for (int n = 0; n < 4; ++n) {
      u16x4 p;
#pragma unroll
      for (int i = 0; i < 4; ++i) p[i] = f2bf(g[it][i][n]);
      *(u16x4*)&xbuf[(n0 + n) * XS + c0] = p;
    }
  }
}

// ---------------------------------------------------------------------------
// One agent step (3 barriers): stage -> K-gemm -> scores || V-gemm -> PV.
// ---------------------------------------------------------------------------
__device__ __forceinline__ void agent_step(
    const f32x4 (&gcur)[2][4], f32x4 (&gnxt)[2][4], int Lnxt, bool do_pf,
    const float* __restrict__ xo_base, u16* __restrict__ xbuf,
    u16* __restrict__ kbuf, u16* __restrict__ vbuf,
    const u16* __restrict__ WKV, const u16x8 (&qp)[4], float (&oacc)[32],
    float& m_run, float& s_run,
    int t, int wave, int col, int quad, int an, int ah) {
  tile_write(gcur, xbuf, t);
  __syncthreads();                                    // B1: xbuf ready
  if (do_pf) tile_load(xo_base + (size_t)Lnxt * 524288, t, gnxt);

  f32x4 acc[4][2];
  gemm_run<4>(WKV, xbuf, wave, col, quad, acc);       // K rows 0..255
#pragma unroll
  for (int mt = 0; mt < 4; ++mt) {
    const int ob = (wave * 4 + mt) * 16 + quad * 4;
#pragma unroll
    for (int nt = 0; nt < 2; ++nt) {
      u16x4 pk;
#pragma unroll
      for (int r = 0; r < 4; ++r) pk[r] = f2bf(acc[mt][nt][r]);
      *(u16x4*)&kbuf[(nt * 16 + col) * XS + ob] = pk;
    }
  }
  __syncthreads();                                    // B2: kbuf ready

  u16x8 ck[4];
#pragma unroll
  for (int jj = 0; jj < 4; ++jj)
    ck[jj] = *(const u16x8*)&kbuf[an * XS + ah * 32 + jj * 8];
  float sc = 0.f;
#pragma unroll
  for (int jj = 0; jj < 4; ++jj)
#pragma unroll
    for (int e = 0; e < 8; ++e) sc += bf2f(qp[jj][e]) * bf2f(ck[jj][e]);
  sc *= 0.17677669529663687f;

  gemm_run<4>(WKV + 65536, xbuf, wave, col, quad, acc);  // V rows 256..511
#pragma unroll
  for (int mt = 0; mt < 4; ++mt) {
    const int ob = (wave * 4 + mt) * 16 + quad * 4;
#pragma unroll
    for (int nt = 0; nt < 2; ++nt) {
      u16x4 pv;
#pragma unroll
      for (int r = 0; r < 4; ++r) pv[r] = f2bf(acc[mt][nt][r]);
      *(u16x4*)&vbuf[(nt * 16 + col) * XS + ob] = pv;
    }
  }
  const float mnew = fmaxf(m_run, sc);
  const float p = __expf(sc - mnew);
  const float al = __expf(m_run - mnew);
  s_run = s_run * al + p;
  m_run = mnew;
  __syncthreads();                                    // B3: vbuf ready

  u16x8 cv[4];
#pragma unroll
  for (int jj = 0; jj < 4; ++jj)
    cv[jj] = *(const u16x8*)&vbuf[an * XS + ah * 32 + jj * 8];
#pragma unroll
  for (int jj = 0; jj < 4; ++jj)
#pragma unroll
    for (int e = 0; e < 8; ++e)
      oacc[jj * 8 + e] = oacc[jj * 8 + e] * al + p * bf2f(cv[jj][e]);
}

// ---------------------------------------------------------------------------
// Fused kernel: grid = cnt*2 (bkl, nh), 256 thr, 3 blocks/CU (52.2 KB LDS).
// ---------------------------------------------------------------------------
__global__ __launch_bounds__(256, 3) void ca_fused(
    const float* __restrict__ ego, const float* __restrict__ other,
    const float* __restrict__ b_oo, const float* __restrict__ b_oe,
    const u16* __restrict__ WCQ, const u16* __restrict__ WKV,
    const u16* __restrict__ WOET, float* __restrict__ Yws,
    float* __restrict__ out, int bk0) {
  // XCD swizzle: put (bk, nh=0/1) pairs on the same XCD (write-line merge).
  int g = blockIdx.x;
  const int nwg = gridDim.x;
  const int gid = ((nwg & 7) == 0) ? ((g & 7) * (nwg >> 3) + (g >> 3)) : g;
  const int bkl = gid >> 1, nh = gid & 1;
  const int bk = bk0 + bkl, b = bk >> 5, kk = bk & 31;
  const int t = threadIdx.x;
  const int lane = t & 63, wave = t >> 6;
  const int col = lane & 15, quad = lane >> 4;
  const int an = t & 31, ah = t >> 5;

  __shared__ u16 xbuf[32 * XS];                       // 16896 B
  __shared__ __align__(16) char bufA[128 * YSF * 4];  // 18432 B (ybuf | kbuf)
  __shared__ u16 bufB[32 * XS];                       // 16896 B (qbuf | vbuf)
  float* ybuf = (float*)bufA;
  u16*   kbuf = (u16*)bufA;
  u16*   qbuf = bufB;
  u16*   vbuf = bufB;

  const float* xe_src  = ego + (size_t)bk * 16384 + nh * 32;
  const float* xo_base = other + (size_t)(b * 256 + kk) * 16384 + nh * 32;

  // ---- phase 0: stage x_e ------------------------------------------------
  f32x4 gA[2][4], gB[2][4];
  tile_load(xe_src, t, gA);
  tile_write(gA, xbuf, t);
  __syncthreads();
  tile_load(xo_base, t, gB);              // prefetch agent 0 (under phase 1)

  // ---- phase 1: Y-gemm + Q-gemm ------------------------------------------
  f32x4 accY[4][2], accQ[4][2];
  gemm_run<4>(WCQ, xbuf, wave, col, quad, accY);           // fused rows
  gemm_run<4>(WCQ + 65536, xbuf, wave, col, quad, accQ);   // q rows
#pragma unroll
  for (int mt = 0; mt < 4; ++mt) {        // Q -> qbuf [n][o]
    const int ob = (wave * 4 + mt) * 16 + quad * 4;
#pragma unroll
    for (int nt = 0; nt < 2; ++nt) {
      u16x4 pq;
#pragma unroll
      for (int r = 0; r < 4; ++r) pq[r] = f2bf(accQ[mt][nt][r]);
      *(u16x4*)&qbuf[(nt * 16 + col) * XS + ob] = pq;
    }
  }
  if (wave < 2) {                         // Y pass A: rows 0..127 -> ybuf
#pragma unroll
    for (int mt = 0; mt < 4; ++mt)
#pragma unroll
      for (int nt = 0; nt < 2; ++nt)
#pragma unroll
        for (int r = 0; r < 4; ++r)
          ybuf[(wave * 64 + mt * 16 + quad * 4 + r) * YSF + nt * 16 + col] =
              accY[mt][nt][r];
  }
  __syncthreads();                        // S1

  // ---- phase 2: q -> regs; Y (+bias) -> Yws, 2 passes --------------------
  u16x8 qp[4];
#pragma unroll
  for (int jj = 0; jj < 4; ++jj)
    qp[jj] = *(const u16x8*)&qbuf[an * XS + ah * 32 + jj * 8];

  const int n4 = (t & 7) * 4, cb = t >> 3;
  float* Ybase = Yws + (size_t)bkl * 16384 + nh * 32 + n4;
#pragma unroll
  for (int it = 0; it < 4; ++it) {
    const int C = cb + it * 32;           // 0..127
    f32x4 v = *(const f32x4*)&ybuf[C * YSF + n4];
    const float bias = b_oo[C];
#pragma unroll
    for (int e = 0; e < 4; ++e) v[e] += bias;
    *(f32x4*)&Ybase[(size_t)C * 64] = v;
  }
  __syncthreads();                        // S2 (ybuf pass-A reads done)
  if (wave >= 2) {                        // Y pass B: rows 128..255
#pragma unroll
    for (int mt = 0; mt < 4; ++mt)
#pragma unroll
      for (int nt = 0; nt < 2; ++nt)
#pragma unroll
        for (int r = 0; r < 4; ++r)
          ybuf[((wave - 2) * 64 + mt * 16 + quad * 4 + r) * YSF + nt * 16 + col] =
              accY[mt][nt][r];
  }
  __syncthreads();                        // S3
#pragma unroll
  for (int it = 0; it < 4; ++it) {
    const int C = 128 + cb + it * 32;     // 128..255
    f32x4 v = *(const f32x4*)&ybuf[(C - 128) * YSF + n4];
    const float bias = b_oo[C];
#pragma unroll
    for (int e = 0; e < 4; ++e) v[e] += bias;
    *(f32x4*)&Ybase[(size_t)C * 64] = v;
  }

  // ---- phase 3: agent loop (3 barriers/step, static gA/gB dbuf) ----------
  float m_run = -3.0e38f, s_run = 0.f;
  float oacc[32];
#pragma unroll
  for (int c = 0; c < 32; ++c) oacc[c] = 0.f;

#pragma unroll 1
  for (int l = 0; l < 8; l += 2) {
    agent_step(gB, gA, l + 1, true, xo_base, xbuf, kbuf, vbuf, WKV,
               qp, oacc, m_run, s_run, t, wave, col, quad, an, ah);
    agent_step(gA, gB, l + 2, (l + 2 < 8), xo_base, xbuf, kbuf, vbuf, WKV,
               qp, oacc, m_run, s_run, t, wave, col, quad, an, ah);
  }

  // ---- phase 4: normalize, out_e GEMM, 2-pass transpose, stores ----------
  {
    const float inv = 1.f / s_run;
#pragma unroll
    for (int jj = 0; jj < 4; ++jj) {
      u16x8 pa;
#pragma unroll
      for (int e = 0; e < 8; ++e) pa[e] = f2bf(oacc[jj * 8 + e] * inv);
      *(u16x8*)&xbuf[an * XS + ah * 32 + jj * 8] = pa;
    }
  }
  __syncthreads();                        // E1

  f32x4 accE[4][2];
  gemm_run<4>(WOET, xbuf, wave, col, quad, accE);
  if (wave < 2) {
#pragma unroll
    for (int mt = 0; mt < 4; ++mt)
#pragma unroll
      for (int nt = 0; nt < 2; ++nt)
#pragma unroll
        for (int r = 0; r < 4; ++r)
          ybuf[(wave * 64 + mt * 16 + quad * 4 + r) * YSF + nt * 16 + col] =
              accE[mt][nt][r];
  }
  __syncthreads();                        // E2
#pragma unroll
  for (int it = 0; it < 4; ++it) {
    const int C = cb + it * 32;
    f32x4 v = *(const f32x4*)&ybuf[C * YSF + n4];
    const float bias = b_oe[C];
#pragma unroll
    for (int e = 0; e < 4; ++e) v[e] += bias;
    *(f32x4*)&out[((size_t)(bk * 256 + C)) * 64 + nh * 32 + n4] = v;
  }
  __syncthreads();                        // E3
  if (wave >= 2) {
#pragma unroll
    for (int mt = 0; mt < 4; ++mt)
#pragma unroll
      for (int nt = 0; nt < 2; ++nt)
#pragma unroll
        for (int r = 0; r < 4; ++r)
          ybuf[((wave - 2) * 64 + mt * 16 + quad * 4 + r) * YSF + nt * 16 + col] =
              accE[mt][nt][r];
  }
  __syncthreads();                        // E4
#pragma unroll
  for (int it = 0; it < 4; ++it) {
    const int C = 128 + cb + it * 32;
    f32x4 v = *(const f32x4*)&ybuf[(C - 128) * YSF + n4];
    const float bias = b_oe[C];
#pragma unroll
    for (int e = 0; e < 4; ++e) v[e] += bias;
    *(f32x4*)&out[((size_t)(bk * 256 + C)) * 64 + nh * 32 + n4] = v;
  }
}

// ---------------------------------------------------------------------------
// out_o broadcast: pure streaming replicate, full-line contiguous stores.
// grid = cnt*4 blocks, 256 thr; thread: 4x (1 f32x4 load -> 8 f32x4 stores).
// ---------------------------------------------------------------------------
__global__ void ca_bcast(const float* __restrict__ Yws,
                         float* __restrict__ out, int bk0) {
  const int t = threadIdx.x;
  float* outO = out + 4194304;
  const size_t base4 = (size_t)blockIdx.x * 1024 + t;   // f32x4 units
#pragma unroll
  for (int it = 0; it < 4; ++it) {
    const size_t idx4 = base4 + (size_t)it * 256;
    const int bkl = (int)(idx4 >> 12);
    const int rem = (int)(idx4 & 4095);
    const int bk = bk0 + bkl, b = bk >> 5, kk = bk & 31;
    const f32x4 v = *(const f32x4*)&Yws[idx4 * 4];
    float* dst = outO + (size_t)(b * 256 + kk) * 16384 + (size_t)rem * 4;
#pragma unroll
    for (int l = 0; l < 8; ++l)
      *(f32x4*)&dst[(size_t)l * 524288] = v;
  }
}

// ---------------------------------------------------------------------------
extern "C" void kernel_launch(void* const* d_in, const int* in_sizes, int n_in,
                              void* d_out, int out_size, void* d_ws,
                              size_t ws_size, hipStream_t stream) {
  const float* ego    = (const float*)d_in[0];
  const float* other  = (const float*)d_in[1];
  const float* Wqkv_e = (const float*)d_in[2];
  const float* Wqkv_o = (const float*)d_in[3];
  const float* Woe    = (const float*)d_in[4];
  const float* boe    = (const float*)d_in[5];
  const float* Woo    = (const float*)d_in[6];
  const float* boo    = (const float*)d_in[7];
  float* out = (float*)d_out;

  u16* WCQ  = (u16*)d_ws;            // [512][256]
  u16* WKV  = WCQ + 512 * 256;       // [512][256]
  u16* WOET = WKV + 512 * 256;       // [256][256]
  float* Yws = (float*)(WOET + 256 * 256);   // nk*16384 f32 (16B-aligned)

  const size_t fixed = (size_t)(512 * 256 + 512 * 256 + 256 * 256) * 2;
  const size_t per_bk = (size_t)16384 * 4;   // Yws slice
  long nk_l = (ws_size > fixed) ? (long)((ws_size - fixed) / per_bk) : 1;
  if (nk_l < 1) nk_l = 1;
  if (nk_l > 256) nk_l = 256;
  const int nk = (int)nk_l;

  ca_setup_fuse<<<256, 256, 0, stream>>>(Wqkv_e, Woo, WCQ);
  ca_setup_trans<<<64, 256, 0, stream>>>(Wqkv_e, Wqkv_o, Woe, WCQ, WKV, WOET);

  for (int bk0 = 0; bk0 < 256; bk0 += nk) {
    const int cnt = (bk0 + nk <= 256) ? nk : (256 - bk0);
    ca_fused<<<cnt * 2, 256, 0, stream>>>(ego, other, boo, boe, WCQ, WKV, WOET,
                                          Yws, out, bk0);
    ca_bcast<<<cnt * 4, 256, 0, stream>>>(Yws, out, bk0);
  }
}

// Round 4
// 565.869 us; speedup vs baseline: 1.0462x; 1.0462x over previous
//
#include <hip/hip_runtime.h>

// ---------------------------------------------------------------------------
// CrossAttention on MI355X (gfx950) — round 6.
//
// v5 post-mortem: FETCH 665 MB vs 151 compulsory, WRITE 244 vs 34 actual;
// MfmaUtil 4.6%. Diagnosis: streaming input evicts the 640 KB weight set from
// per-XCD L2 (1.34 GB weight reads -> ~38% HBM miss) and half-line Y/out
// stores get evicted before the nh-partner merges -> write amplification.
//
// v6 (single lever): non-temporal hints on all strictly-streaming traffic
// (input staging loads, bcast load/store) so L2 keeps weights + merging
// half-lines. Y/out_e stores stay cached (must merge with co-XCD partner).
//
// ws: [WCQ 512x256 bf16][WKV 512x256][WOET 256x256][Yws nk*16384 f32]
// ---------------------------------------------------------------------------

typedef unsigned short u16;
typedef u16  u16x8 __attribute__((ext_vector_type(8)));
typedef u16  u16x4 __attribute__((ext_vector_type(4)));
typedef __bf16 bf16x8 __attribute__((ext_vector_type(8)));
typedef float f32x4 __attribute__((ext_vector_type(4)));

#define XS  264   // LDS stride (u16) for 256-wide bf16 tiles
#define YSF 36    // LDS stride (f32) for 128x32 f32 transpose buffer

__device__ __forceinline__ u16 f2bf(float f) {
  union { float f; unsigned u; } t; t.f = f;
  unsigned r = t.u + 0x7FFF + ((t.u >> 16) & 1);
  return (u16)(r >> 16);
}
__device__ __forceinline__ float bf2f(u16 x) {
  union { unsigned u; float f; } t; t.u = ((unsigned)x) << 16;
  return t.f;
}

// D[o][n] = sum_c WT[o][c]*X[n][c]; rows = MT*4*16, N = 32, K = 256.
// WT from global (L2-resident weights), X from LDS [n][XS].
template <int MT>
__device__ __forceinline__ void gemm_run(const u16* __restrict__ WT,
                                         const u16* __restrict__ X,
                                         int wave, int col, int quad,
                                         f32x4 (&acc)[MT][2]) {
#pragma unroll
  for (int mt = 0; mt < MT; ++mt)
#pragma unroll
    for (int nt = 0; nt < 2; ++nt)
      acc[mt][nt] = (f32x4)(0.0f);
  for (int ks = 0; ks < 8; ++ks) {
    bf16x8 bfr[2];
#pragma unroll
    for (int nt = 0; nt < 2; ++nt)
      bfr[nt] = __builtin_bit_cast(
          bf16x8, *(const u16x8*)&X[(nt * 16 + col) * XS + ks * 32 + quad * 8]);
#pragma unroll
    for (int mt = 0; mt < MT; ++mt) {
      const int m = (wave * MT + mt) * 16 + col;
      bf16x8 afr = __builtin_bit_cast(
          bf16x8, *(const u16x8*)&WT[m * 256 + ks * 32 + quad * 8]);
#pragma unroll
      for (int nt = 0; nt < 2; ++nt)
        acc[mt][nt] = __builtin_amdgcn_mfma_f32_16x16x32_bf16(
            afr, bfr[nt], acc[mt][nt], 0, 0, 0);
    }
  }
}

// ---------------------------------------------------------------------------
// Setup: WCQ rows 0..255 = (Wv_ego @ W_out_other)^T, rows 256..511 = Wq_ego^T
// ---------------------------------------------------------------------------
__global__ void ca_setup_fuse(const float* __restrict__ Wqkv_e,
                              const float* __restrict__ Woo,
                              u16* __restrict__ WCQ) {
  const int c = blockIdx.x, o = threadIdx.x;
  __shared__ float wv[256];
  wv[o] = Wqkv_e[c * 768 + 512 + o];
  __syncthreads();
  float s = 0.f;
#pragma unroll 8
  for (int j = 0; j < 256; ++j) s += wv[j] * Woo[j * 256 + o];
  WCQ[o * 256 + c] = f2bf(s);
}

// Tiled 64x64 LDS transpose for the three weight sections.
__global__ void ca_setup_trans(const float* __restrict__ Wqkv_e,
                               const float* __restrict__ Wqkv_o,
                               const float* __restrict__ Woe,
                               u16* __restrict__ WCQ, u16* __restrict__ WKV,
                               u16* __restrict__ WOET) {
  const int bid = blockIdx.x;               // 64 blocks: job(2b)|ot(2b)|ct(2b)
  const int job = bid >> 4, ot = (bid >> 2) & 3, ct = bid & 3;
  const float* src; int stride, coff; u16* dst;
  if (job == 0)      { src = Wqkv_e; stride = 768; coff = 0;   dst = WCQ + 65536; }
  else if (job == 1) { src = Wqkv_o; stride = 768; coff = 256; dst = WKV; }
  else if (job == 2) { src = Wqkv_o; stride = 768; coff = 512; dst = WKV + 65536; }
  else               { src = Woe;    stride = 256; coff = 0;   dst = WOET; }
  __shared__ float tile[64][65];
  const int t = threadIdx.x, tc = t & 15, tr = t >> 4;   // tr in [0,16)
#pragma unroll
  for (int j = 0; j < 4; ++j) {
    const int cl = tr + j * 16;                          // local src row
    const f32x4 v =
        *(const f32x4*)&src[(ct * 64 + cl) * stride + coff + ot * 64 + tc * 4];
#pragma unroll
    for (int e = 0; e < 4; ++e) tile[cl][tc * 4 + e] = v[e];
  }
  __syncthreads();
#pragma unroll
  for (int j = 0; j < 4; ++j) {
    const int ol = tr + j * 16;                          // local dst row (o)
    u16x4 p;
#pragma unroll
    for (int e = 0; e < 4; ++e) p[e] = f2bf(tile[tc * 4 + e][ol]);
    *(u16x4*)&dst[(ot * 64 + ol) * 256 + ct * 64 + tc * 4] = p;
  }
}

// ---------------------------------------------------------------------------
// Tile staging: 32 pixels x 256 ch, f32 [c][64] global -> bf16 [n][c] LDS.
// Loads are NON-TEMPORAL: strictly read-once stream, must not evict weights.
// ---------------------------------------------------------------------------
__device__ __forceinline__ void tile_load(const float* __restrict__ src, int t,
                                          f32x4 (&g)[2][4]) {
#pragma unroll
  for (int it = 0; it < 2; ++it) {
    const int id = t + it * 256;
    const int n0 = (id & 7) * 4, c0 = (id >> 3) * 4;
#pragma unroll
    for (int i = 0; i < 4; ++i)
      g[it][i] = __builtin_nontemporal_load(
          (const f32x4*)&src[(c0 + i) * 64 + n0]);
  }
}
__device__ __forceinline__ void tile_write(const f32x4 (&g)[2][4],
                                           u16* __restrict__ xbuf, int t) {
#pragma unroll
  for (int it = 0; it < 2; ++it) {
    const int id = t + it * 256;
    const int n0 = (id & 7) * 4, c0 = (id >> 3) * 4;
#pragma unroll
    for (int n = 0; n < 4; ++n) {
      u16x4 p;
#pragma unroll
      for (int i = 0; i < 4; ++i) p[i] = f2bf(g[it][i][n]);
      *(u16x4*)&xbuf[(n0 + n) * XS + c0] = p;
    }
  }
}

// ---------------------------------------------------------------------------
// One agent step (3 barriers): stage -> K-gemm -> scores || V-gemm -> PV.
// ---------------------------------------------------------------------------
__device__ __forceinline__ void agent_step(
    const f32x4 (&gcur)[2][4], f32x4 (&gnxt)[2][4], int Lnxt, bool do_pf,
    const float* __restrict__ xo_base, u16* __restrict__ xbuf,
    u16* __restrict__ kbuf, u16* __restrict__ vbuf,
    const u16* __restrict__ WKV, const u16x8 (&qp)[4], float (&oacc)[32],
    float& m_run, float& s_run,
    int t, int wave, int col, int quad, int an, int ah) {
  tile_write(gcur, xbuf, t);
  __syncthreads();                                    // B1: xbuf ready
  if (do_pf) tile_load(xo_base + (size_t)Lnxt * 524288, t, gnxt);

  f32x4 acc[4][2];
  gemm_run<4>(WKV, xbuf, wave, col, quad, acc);       // K rows 0..255
#pragma unroll
  for (int mt = 0; mt < 4; ++mt) {
    const int ob = (wave * 4 + mt) * 16 + quad * 4;
#pragma unroll
    for (int nt = 0; nt < 2; ++nt) {
      u16x4 pk;
#pragma unroll
      for (int r = 0; r < 4; ++r) pk[r] = f2bf(acc[mt][nt][r]);
      *(u16x4*)&kbuf[(nt * 16 + col) * XS + ob] = pk;
    }
  }
  __syncthreads();                                    // B2: kbuf ready

  u16x8 ck[4];
#pragma unroll
  for (int jj = 0; jj < 4; ++jj)
    ck[jj] = *(const u16x8*)&kbuf[an * XS + ah * 32 + jj * 8];
  float sc = 0.f;
#pragma unroll
  for (int jj = 0; jj < 4; ++jj)
#pragma unroll
    for (int e = 0; e < 8; ++e) sc += bf2f(qp[jj][e]) * bf2f(ck[jj][e]);
  sc *= 0.17677669529663687f;

  gemm_run<4>(WKV + 65536, xbuf, wave, col, quad, acc);  // V rows 256..511
#pragma unroll
  for (int mt = 0; mt < 4; ++mt) {
    const int ob = (wave * 4 + mt) * 16 + quad * 4;
#pragma unroll
    for (int nt = 0; nt < 2; ++nt) {
      u16x4 pv;
#pragma unroll
      for (int r = 0; r < 4; ++r) pv[r] = f2bf(acc[mt][nt][r]);
      *(u16x4*)&vbuf[(nt * 16 + col) * XS + ob] = pv;
    }
  }
  const float mnew = fmaxf(m_run, sc);
  const float p = __expf(sc - mnew);
  const float al = __expf(m_run - mnew);
  s_run = s_run * al + p;
  m_run = mnew;
  __syncthreads();                                    // B3: vbuf ready

  u16x8 cv[4];
#pragma unroll
  for (int jj = 0; jj < 4; ++jj)
    cv[jj] = *(const u16x8*)&vbuf[an * XS + ah * 32 + jj * 8];
#pragma unroll
  for (int jj = 0; jj < 4; ++jj)
#pragma unroll
    for (int e = 0; e < 8; ++e)
      oacc[jj * 8 + e] = oacc[jj * 8 + e] * al + p * bf2f(cv[jj][e]);
}

// ---------------------------------------------------------------------------
// Fused kernel: grid = cnt*2 (bkl, nh), 256 thr, 3 blocks/CU (52.2 KB LDS).
// ---------------------------------------------------------------------------
__global__ __launch_bounds__(256, 3) void ca_fused(
    const float* __restrict__ ego, const float* __restrict__ other,
    const float* __restrict__ b_oo, const float* __restrict__ b_oe,
    const u16* __restrict__ WCQ, const u16* __restrict__ WKV,
    const u16* __restrict__ WOET, float* __restrict__ Yws,
    float* __restrict__ out, int bk0) {
  // XCD swizzle: put (bk, nh=0/1) pairs on the same XCD (write-line merge).
  int g = blockIdx.x;
  const int nwg = gridDim.x;
  const int gid = ((nwg & 7) == 0) ? ((g & 7) * (nwg >> 3) + (g >> 3)) : g;
  const int bkl = gid >> 1, nh = gid & 1;
  const int bk = bk0 + bkl, b = bk >> 5, kk = bk & 31;
  const int t = threadIdx.x;
  const int lane = t & 63, wave = t >> 6;
  const int col = lane & 15, quad = lane >> 4;
  const int an = t & 31, ah = t >> 5;

  __shared__ u16 xbuf[32 * XS];                       // 16896 B
  __shared__ __align__(16) char bufA[128 * YSF * 4];  // 18432 B (ybuf | kbuf)
  __shared__ u16 bufB[32 * XS];                       // 16896 B (qbuf | vbuf)
  float* ybuf = (float*)bufA;
  u16*   kbuf = (u16*)bufA;
  u16*   qbuf = bufB;
  u16*   vbuf = bufB;

  const float* xe_src  = ego + (size_t)bk * 16384 + nh * 32;
  const float* xo_base = other + (size_t)(b * 256 + kk) * 16384 + nh * 32;

  // ---- phase 0: stage x_e ------------------------------------------------
  f32x4 gA[2][4], gB[2][4];
  tile_load(xe_src, t, gA);
  tile_write(gA, xbuf, t);
  __syncthreads();
  tile_load(xo_base, t, gB);              // prefetch agent 0 (under phase 1)

  // ---- phase 1: Y-gemm + Q-gemm ------------------------------------------
  f32x4 accY[4][2], accQ[4][2];
  gemm_run<4>(WCQ, xbuf, wave, col, quad, accY);           // fused rows
  gemm_run<4>(WCQ + 65536, xbuf, wave, col, quad, accQ);   // q rows
#pragma unroll
  for (int mt = 0; mt < 4; ++mt) {        // Q -> qbuf [n][o]
    const int ob = (wave * 4 + mt) * 16 + quad * 4;
#pragma unroll
    for (int nt = 0; nt < 2; ++nt) {
      u16x4 pq;
#pragma unroll
      for (int r = 0; r < 4; ++r) pq[r] = f2bf(accQ[mt][nt][r]);
      *(u16x4*)&qbuf[(nt * 16 + col) * XS + ob] = pq;
    }
  }
  if (wave < 2) {                         // Y pass A: rows 0..127 -> ybuf
#pragma unroll
    for (int mt = 0; mt < 4; ++mt)
#pragma unroll
      for (int nt = 0; nt < 2; ++nt)
#pragma unroll
        for (int r = 0; r < 4; ++r)
          ybuf[(wave * 64 + mt * 16 + quad * 4 + r) * YSF + nt * 16 + col] =
              accY[mt][nt][r];
  }
  __syncthreads();                        // S1

  // ---- phase 2: q -> regs; Y (+bias) -> Yws, 2 passes --------------------
  u16x8 qp[4];
#pragma unroll
  for (int jj = 0; jj < 4; ++jj)
    qp[jj] = *(const u16x8*)&qbuf[an * XS + ah * 32 + jj * 8];

  const int n4 = (t & 7) * 4, cb = t >> 3;
  float* Ybase = Yws + (size_t)bkl * 16384 + nh * 32 + n4;
#pragma unroll
  for (int it = 0; it < 4; ++it) {
    const int C = cb + it * 32;           // 0..127
    f32x4 v = *(const f32x4*)&ybuf[C * YSF + n4];
    const float bias = b_oo[C];
#pragma unroll
    for (int e = 0; e < 4; ++e) v[e] += bias;
    *(f32x4*)&Ybase[(size_t)C * 64] = v;
  }
  __syncthreads();                        // S2 (ybuf pass-A reads done)
  if (wave >= 2) {                        // Y pass B: rows 128..255
#pragma unroll
    for (int mt = 0; mt < 4; ++mt)
#pragma unroll
      for (int nt = 0; nt < 2; ++nt)
#pragma unroll
        for (int r = 0; r < 4; ++r)
          ybuf[((wave - 2) * 64 + mt * 16 + quad * 4 + r) * YSF + nt * 16 + col] =
              accY[mt][nt][r];
  }
  __syncthreads();                        // S3
#pragma unroll
  for (int it = 0; it < 4; ++it) {
    const int C = 128 + cb + it * 32;     // 128..255
    f32x4 v = *(const f32x4*)&ybuf[(C - 128) * YSF + n4];
    const float bias = b_oo[C];
#pragma unroll
    for (int e = 0; e < 4; ++e) v[e] += bias;
    *(f32x4*)&Ybase[(size_t)C * 64] = v;
  }

  // ---- phase 3: agent loop (3 barriers/step, static gA/gB dbuf) ----------
  float m_run = -3.0e38f, s_run = 0.f;
  float oacc[32];
#pragma unroll
  for (int c = 0; c < 32; ++c) oacc[c] = 0.f;

#pragma unroll 1
  for (int l = 0; l < 8; l += 2) {
    agent_step(gB, gA, l + 1, true, xo_base, xbuf, kbuf, vbuf, WKV,
               qp, oacc, m_run, s_run, t, wave, col, quad, an, ah);
    agent_step(gA, gB, l + 2, (l + 2 < 8), xo_base, xbuf, kbuf, vbuf, WKV,
               qp, oacc, m_run, s_run, t, wave, col, quad, an, ah);
  }

  // ---- phase 4: normalize, out_e GEMM, 2-pass transpose, stores ----------
  {
    const float inv = 1.f / s_run;
#pragma unroll
    for (int jj = 0; jj < 4; ++jj) {
      u16x8 pa;
#pragma unroll
      for (int e = 0; e < 8; ++e) pa[e] = f2bf(oacc[jj * 8 + e] * inv);
      *(u16x8*)&xbuf[an * XS + ah * 32 + jj * 8] = pa;
    }
  }
  __syncthreads();                        // E1

  f32x4 accE[4][2];
  gemm_run<4>(WOET, xbuf, wave, col, quad, accE);
  if (wave < 2) {
#pragma unroll
    for (int mt = 0; mt < 4; ++mt)
#pragma unroll
      for (int nt = 0; nt < 2; ++nt)
#pragma unroll
        for (int r = 0; r < 4; ++r)
          ybuf[(wave * 64 + mt * 16 + quad * 4 + r) * YSF + nt * 16 + col] =
              accE[mt][nt][r];
  }
  __syncthreads();                        // E2
#pragma unroll
  for (int it = 0; it < 4; ++it) {
    const int C = cb + it * 32;
    f32x4 v = *(const f32x4*)&ybuf[C * YSF + n4];
    const float bias = b_oe[C];
#pragma unroll
    for (int e = 0; e < 4; ++e) v[e] += bias;
    *(f32x4*)&out[((size_t)(bk * 256 + C)) * 64 + nh * 32 + n4] = v;
  }
  __syncthreads();                        // E3
  if (wave >= 2) {
#pragma unroll
    for (int mt = 0; mt < 4; ++mt)
#pragma unroll
      for (int nt = 0; nt < 2; ++nt)
#pragma unroll
        for (int r = 0; r < 4; ++r)
          ybuf[((wave - 2) * 64 + mt * 16 + quad * 4 + r) * YSF + nt * 16 + col] =
              accE[mt][nt][r];
  }
  __syncthreads();                        // E4
#pragma unroll
  for (int it = 0; it < 4; ++it) {
    const int C = 128 + cb + it * 32;
    f32x4 v = *(const f32x4*)&ybuf[(C - 128) * YSF + n4];
    const float bias = b_oe[C];
#pragma unroll
    for (int e = 0; e < 4; ++e) v[e] += bias;
    *(f32x4*)&out[((size_t)(bk * 256 + C)) * 64 + nh * 32 + n4] = v;
  }
}

// ---------------------------------------------------------------------------
// out_o broadcast: pure streaming replicate, full-line contiguous stores.
// Fully non-temporal: zero reuse, must not touch weight-resident L2.
// ---------------------------------------------------------------------------
__global__ void ca_bcast(const float* __restrict__ Yws,
                         float* __restrict__ out, int bk0) {
  const int t = threadIdx.x;
  float* outO = out + 4194304;
  const size_t base4 = (size_t)blockIdx.x * 1024 + t;   // f32x4 units
#pragma unroll
  for (int it = 0; it < 4; ++it) {
    const size_t idx4 = base4 + (size_t)it * 256;
    const int bkl = (int)(idx4 >> 12);
    const int rem = (int)(idx4 & 4095);
    const int bk = bk0 + bkl, b = bk >> 5, kk = bk & 31;
    const f32x4 v = __builtin_nontemporal_load((const f32x4*)&Yws[idx4 * 4]);
    float* dst = outO + (size_t)(b * 256 + kk) * 16384 + (size_t)rem * 4;
#pragma unroll
    for (int l = 0; l < 8; ++l)
      __builtin_nontemporal_store(v, (f32x4*)&dst[(size_t)l * 524288]);
  }
}

// ---------------------------------------------------------------------------
extern "C" void kernel_launch(void* const* d_in, const int* in_sizes, int n_in,
                              void* d_out, int out_size, void* d_ws,
                              size_t ws_size, hipStream_t stream) {
  const float* ego    = (const float*)d_in[0];
  const float* other  = (const float*)d_in[1];
  const float* Wqkv_e = (const float*)d_in[2];
  const float* Wqkv_o = (const float*)d_in[3];
  const float* Woe    = (const float*)d_in[4];
  const float* boe    = (const float*)d_in[5];
  const float* Woo    = (const float*)d_in[6];
  const float* boo    = (const float*)d_in[7];
  float* out = (float*)d_out;

  u16* WCQ  = (u16*)d_ws;            // [512][256]
  u16* WKV  = WCQ + 512 * 256;       // [512][256]
  u16* WOET = WKV + 512 * 256;       // [256][256]
  float* Yws = (float*)(WOET + 256 * 256);   // nk*16384 f32 (16B-aligned)

  const size_t fixed = (size_t)(512 * 256 + 512 * 256 + 256 * 256) * 2;
  const size_t per_bk = (size_t)16384 * 4;   // Yws slice
  long nk_l = (ws_size > fixed) ? (long)((ws_size - fixed) / per_bk) : 1;
  if (nk_l < 1) nk_l = 1;
  if (nk_l > 256) nk_l = 256;
  const int nk = (int)nk_l;

  ca_setup_fuse<<<256, 256, 0, stream>>>(Wqkv_e, Woo, WCQ);
  ca_setup_trans<<<64, 256, 0, stream>>>(Wqkv_e, Wqkv_o, Woe, WCQ, WKV, WOET);

  for (int bk0 = 0; bk0 < 256; bk0 += nk) {
    const int cnt = (bk0 + nk <= 256) ? nk : (256 - bk0);
    ca_fused<<<cnt * 2, 256, 0, stream>>>(ego, other, boo, boe, WCQ, WKV, WOET,
                                          Yws, out, bk0);
    ca_bcast<<<cnt * 4, 256, 0, stream>>>(Yws, out, bk0);
  }
}

// Round 5
// 384.048 us; speedup vs baseline: 1.5414x; 1.4734x over previous
//
#include <hip/hip_runtime.h>

// ---------------------------------------------------------------------------
// CrossAttention on MI355X (gfx950) — round 7.
//
// v6 post-mortem: nt hints changed nothing (FETCH 667 MB both). Excess fetch
// is weight re-reads: 512 blocks x 2.4 MB = 1.23 GB issued, ~40% HBM miss.
// Weight traffic scales with #blocks only.
//
// v7:
//  * N=64: merge both nh halves per block -> grid 256 x 512 thr. Weight
//    traffic issued halves (614 MB). Same 8 waves/CU. All rows full-line.
//  * out_o broadcast folded into prologue (8x nontemporal full-line copies
//    from the Y transpose); ca_bcast kernel + Yws round-trip deleted.
//  * K/V share one LDS buffer (extra barrier per step); LDS 100 KB, 1 blk/CU.
//
// ws: [WCQ 512x256 bf16][WKV 512x256][WOET 256x256]  (weights only)
// ---------------------------------------------------------------------------

typedef unsigned short u16;
typedef u16  u16x8 __attribute__((ext_vector_type(8)));
typedef u16  u16x4 __attribute__((ext_vector_type(4)));
typedef __bf16 bf16x8 __attribute__((ext_vector_type(8)));
typedef float f32x4 __attribute__((ext_vector_type(4)));

#define XS   264   // LDS stride (u16) for 256-wide bf16 tiles (64 rows)
#define QS   272   // LDS stride (u16) for qbuf rows (union with ybuf [128][68])
#define YSF  68    // LDS stride (f32) for 128x64 f32 transpose buffer

__device__ __forceinline__ u16 f2bf(float f) {
  union { float f; unsigned u; } t; t.f = f;
  unsigned r = t.u + 0x7FFF + ((t.u >> 16) & 1);
  return (u16)(r >> 16);
}
__device__ __forceinline__ float bf2f(u16 x) {
  union { unsigned u; float f; } t; t.u = ((unsigned)x) << 16;
  return t.f;
}

// D[o][n] = sum_c WT[o][c]*X[n][c]; M = 8*MT*16 rows, N = 64, K = 256.
// 8 waves; WT from global (L2 weights), X from LDS [n][XS].
template <int MT>
__device__ __forceinline__ void gemm_run(const u16* __restrict__ WT,
                                         const u16* __restrict__ X,
                                         int wave, int col, int quad,
                                         f32x4 (&acc)[MT][4]) {
#pragma unroll
  for (int mt = 0; mt < MT; ++mt)
#pragma unroll
    for (int nt = 0; nt < 4; ++nt)
      acc[mt][nt] = (f32x4)(0.0f);
  for (int ks = 0; ks < 8; ++ks) {
    bf16x8 bfr[4];
#pragma unroll
    for (int nt = 0; nt < 4; ++nt)
      bfr[nt] = __builtin_bit_cast(
          bf16x8, *(const u16x8*)&X[(nt * 16 + col) * XS + ks * 32 + quad * 8]);
#pragma unroll
    for (int mt = 0; mt < MT; ++mt) {
      const int m = (wave * MT + mt) * 16 + col;
      bf16x8 afr = __builtin_bit_cast(
          bf16x8, *(const u16x8*)&WT[m * 256 + ks * 32 + quad * 8]);
#pragma unroll
      for (int nt = 0; nt < 4; ++nt)
        acc[mt][nt] = __builtin_amdgcn_mfma_f32_16x16x32_bf16(
            afr, bfr[nt], acc[mt][nt], 0, 0, 0);
    }
  }
}

// ---------------------------------------------------------------------------
// Setup: WCQ rows 0..255 = (Wv_ego @ W_out_other)^T, rows 256..511 = Wq_ego^T
// ---------------------------------------------------------------------------
__global__ void ca_setup_fuse(const float* __restrict__ Wqkv_e,
                              const float* __restrict__ Woo,
                              u16* __restrict__ WCQ) {
  const int c = blockIdx.x, o = threadIdx.x;
  __shared__ float wv[256];
  wv[o] = Wqkv_e[c * 768 + 512 + o];
  __syncthreads();
  float s = 0.f;
#pragma unroll 8
  for (int j = 0; j < 256; ++j) s += wv[j] * Woo[j * 256 + o];
  WCQ[o * 256 + c] = f2bf(s);
}

// Tiled 64x64 LDS transpose for the three weight sections.
__global__ void ca_setup_trans(const float* __restrict__ Wqkv_e,
                               const float* __restrict__ Wqkv_o,
                               const float* __restrict__ Woe,
                               u16* __restrict__ WCQ, u16* __restrict__ WKV,
                               u16* __restrict__ WOET) {
  const int bid = blockIdx.x;               // 64 blocks: job(2b)|ot(2b)|ct(2b)
  const int job = bid >> 4, ot = (bid >> 2) & 3, ct = bid & 3;
  const float* src; int stride, coff; u16* dst;
  if (job == 0)      { src = Wqkv_e; stride = 768; coff = 0;   dst = WCQ + 65536; }
  else if (job == 1) { src = Wqkv_o; stride = 768; coff = 256; dst = WKV; }
  else if (job == 2) { src = Wqkv_o; stride = 768; coff = 512; dst = WKV + 65536; }
  else               { src = Woe;    stride = 256; coff = 0;   dst = WOET; }
  __shared__ float tile[64][65];
  const int t = threadIdx.x, tc = t & 15, tr = t >> 4;   // tr in [0,16)
#pragma unroll
  for (int j = 0; j < 4; ++j) {
    const int cl = tr + j * 16;                          // local src row
    const f32x4 v =
        *(const f32x4*)&src[(ct * 64 + cl) * stride + coff + ot * 64 + tc * 4];
#pragma unroll
    for (int e = 0; e < 4; ++e) tile[cl][tc * 4 + e] = v[e];
  }
  __syncthreads();
#pragma unroll
  for (int j = 0; j < 4; ++j) {
    const int ol = tr + j * 16;                          // local dst row (o)
    u16x4 p;
#pragma unroll
    for (int e = 0; e < 4; ++e) p[e] = f2bf(tile[tc * 4 + e][ol]);
    *(u16x4*)&dst[(ot * 64 + ol) * 256 + ct * 64 + tc * 4] = p;
  }
}

// ---------------------------------------------------------------------------
// Tile staging: 64 pixels x 256 ch, f32 [c][64] global -> bf16 [n][c] LDS.
// Thread t: 2 micro-tiles of 4c x 4n; 16 lanes cover a full 256 B row.
// ---------------------------------------------------------------------------
__device__ __forceinline__ void tile_load(const float* __restrict__ src, int t,
                                          f32x4 (&g)[2][4]) {
#pragma unroll
  for (int it = 0; it < 2; ++it) {
    const int id = t + it * 512;
    const int n0 = (id & 15) * 4, c0 = (id >> 4) * 4;
#pragma unroll
    for (int i = 0; i < 4; ++i)
      g[it][i] = __builtin_nontemporal_load(
          (const f32x4*)&src[(c0 + i) * 64 + n0]);
  }
}
__device__ __forceinline__ void tile_write(const f32x4 (&g)[2][4],
                                           u16* __restrict__ xbuf, int t) {
#pragma unroll
  for (int it = 0; it < 2; ++it) {
    const int id = t + it * 512;
    const int n0 = (id & 15) * 4, c0 = (id >> 4) * 4;
#pragma unroll
    for (int n = 0; n < 4; ++n) {
      u16x4 p;
#pragma unroll
      for (int i = 0; i < 4; ++i) p[i] = f2bf(g[it][i][n]);
      *(u16x4*)&xbuf[(n0 + n) * XS + c0] = p;
    }
  }
}

// ---------------------------------------------------------------------------
// One agent step (4 barriers): stage -> K-gemm -> scores -> V-gemm -> PV.
// K and V time-share kvbuf.
// ---------------------------------------------------------------------------
__device__ __forceinline__ void agent_step(
    const f32x4 (&gcur)[2][4], f32x4 (&gnxt)[2][4], int Lnxt, bool do_pf,
    const float* __restrict__ xo_base, u16* __restrict__ xbuf,
    u16* __restrict__ kvbuf, const u16* __restrict__ WKV,
    const u16x8 (&qp)[4], float (&oacc)[32], float& m_run, float& s_run,
    int t, int wave, int col, int quad, int an, int ah) {
  tile_write(gcur, xbuf, t);
  __syncthreads();                                    // B1: xbuf ready
  if (do_pf) tile_load(xo_base + (size_t)Lnxt * 524288, t, gnxt);

  f32x4 acc[2][4];
  gemm_run<2>(WKV, xbuf, wave, col, quad, acc);       // K rows 0..255
#pragma unroll
  for (int mt = 0; mt < 2; ++mt) {
    const int ob = (wave * 2 + mt) * 16 + quad * 4;
#pragma unroll
    for (int nt = 0; nt < 4; ++nt) {
      u16x4 pk;
#pragma unroll
      for (int r = 0; r < 4; ++r) pk[r] = f2bf(acc[mt][nt][r]);
      *(u16x4*)&kvbuf[(nt * 16 + col) * XS + ob] = pk;
    }
  }
  __syncthreads();                                    // B2: kbuf ready

  u16x8 ck[4];
#pragma unroll
  for (int jj = 0; jj < 4; ++jj)
    ck[jj] = *(const u16x8*)&kvbuf[an * XS + ah * 32 + jj * 8];
  __syncthreads();                                    // B2b: ck reads done

  float sc = 0.f;
#pragma unroll
  for (int jj = 0; jj < 4; ++jj)
#pragma unroll
    for (int e = 0; e < 8; ++e) sc += bf2f(qp[jj][e]) * bf2f(ck[jj][e]);
  sc *= 0.17677669529663687f;

  gemm_run<2>(WKV + 65536, xbuf, wave, col, quad, acc);  // V rows 256..511
#pragma unroll
  for (int mt = 0; mt < 2; ++mt) {
    const int ob = (wave * 2 + mt) * 16 + quad * 4;
#pragma unroll
    for (int nt = 0; nt < 4; ++nt) {
      u16x4 pv;
#pragma unroll
      for (int r = 0; r < 4; ++r) pv[r] = f2bf(acc[mt][nt][r]);
      *(u16x4*)&kvbuf[(nt * 16 + col) * XS + ob] = pv;
    }
  }
  const float mnew = fmaxf(m_run, sc);
  const float p = __expf(sc - mnew);
  const float al = __expf(m_run - mnew);
  s_run = s_run * al + p;
  m_run = mnew;
  __syncthreads();                                    // B3: vbuf ready

  u16x8 cv[4];
#pragma unroll
  for (int jj = 0; jj < 4; ++jj)
    cv[jj] = *(const u16x8*)&kvbuf[an * XS + ah * 32 + jj * 8];
#pragma unroll
  for (int jj = 0; jj < 4; ++jj)
#pragma unroll
    for (int e = 0; e < 8; ++e)
      oacc[jj * 8 + e] = oacc[jj * 8 + e] * al + p * bf2f(cv[jj][e]);
}

// ---------------------------------------------------------------------------
// Fused kernel: grid = 256 (bk), 512 thr (8 waves), 1 block/CU, LDS 100 KB.
// ---------------------------------------------------------------------------
__global__ __launch_bounds__(512, 2) void ca_fused(
    const float* __restrict__ ego, const float* __restrict__ other,
    const float* __restrict__ b_oo, const float* __restrict__ b_oe,
    const u16* __restrict__ WCQ, const u16* __restrict__ WKV,
    const u16* __restrict__ WOET, float* __restrict__ out) {
  // XCD swizzle (bijective: 256 % 8 == 0): contiguous bk chunk per XCD.
  const int g = blockIdx.x;
  const int bk = (g & 7) * 32 + (g >> 3);
  const int b = bk >> 5, kk = bk & 31;
  const int t = threadIdx.x;
  const int lane = t & 63, wave = t >> 6;
  const int col = lane & 15, quad = lane >> 4;
  const int an = t & 63, ah = t >> 6;     // attention: pixel 0..63, head 0..7

  __shared__ u16 xbuf[64 * XS];                        // 33792 B
  __shared__ u16 kvbuf[64 * XS];                       // 33792 B
  __shared__ __align__(16) char ubuf[64 * QS * 2];     // 34816 B (qbuf|ybuf)
  u16*   qbuf = (u16*)ubuf;                            // [64][QS]
  float* ybuf = (float*)ubuf;                          // [128][YSF]

  const float* xe_src  = ego + (size_t)bk * 16384;
  const float* xo_base = other + (size_t)(b * 256 + kk) * 16384;
  float* outO = out + 4194304;

  // ---- phase 0: stage x_e (all 64 px) ------------------------------------
  f32x4 gA[2][4], gB[2][4];
  tile_load(xe_src, t, gA);
  tile_write(gA, xbuf, t);
  __syncthreads();
  tile_load(xo_base, t, gB);              // prefetch agent 0 (under prologue)

  // ---- phase 1: Y-gemm + Q-gemm (each M=256, N=64) -----------------------
  f32x4 accY[2][4], accQ[2][4];
  gemm_run<2>(WCQ, xbuf, wave, col, quad, accY);           // fused rows
  gemm_run<2>(WCQ + 65536, xbuf, wave, col, quad, accQ);   // q rows
#pragma unroll
  for (int mt = 0; mt < 2; ++mt) {        // Q -> qbuf [n][o]
    const int ob = (wave * 2 + mt) * 16 + quad * 4;
#pragma unroll
    for (int nt = 0; nt < 4; ++nt) {
      u16x4 pq;
#pragma unroll
      for (int r = 0; r < 4; ++r) pq[r] = f2bf(accQ[mt][nt][r]);
      *(u16x4*)&qbuf[(nt * 16 + col) * QS + ob] = pq;
    }
  }
  __syncthreads();                        // S1: qbuf ready

  u16x8 qp[4];
#pragma unroll
  for (int jj = 0; jj < 4; ++jj)
    qp[jj] = *(const u16x8*)&qbuf[an * QS + ah * 32 + jj * 8];
  __syncthreads();                        // S2: q reads done, ubuf -> ybuf

  // ---- phase 2: Y transpose + biased 8x broadcast to out_o, 2 passes -----
  const int n4 = (t & 15) * 4, cb = t >> 4;    // n4 in [0,64), cb in [0,32)
  const size_t obase = (size_t)(b * 256 + kk) * 16384;

  if (wave < 4) {                         // pass A: Y rows 0..127
#pragma unroll
    for (int mt = 0; mt < 2; ++mt)
#pragma unroll
      for (int nt = 0; nt < 4; ++nt)
#pragma unroll
        for (int r = 0; r < 4; ++r)
          ybuf[(wave * 32 + mt * 16 + quad * 4 + r) * YSF + nt * 16 + col] =
              accY[mt][nt][r];
  }
  __syncthreads();                        // S3
#pragma unroll
  for (int it = 0; it < 4; ++it) {
    const int C = cb + it * 32;           // 0..127
    f32x4 v = *(const f32x4*)&ybuf[C * YSF + n4];
    const float bias = b_oo[C];
#pragma unroll
    for (int e = 0; e < 4; ++e) v[e] += bias;
#pragma unroll
    for (int l = 0; l < 8; ++l)
      __builtin_nontemporal_store(
          v, (f32x4*)&outO[obase + (size_t)l * 524288 + C * 64 + n4]);
  }
  __syncthreads();                        // S4
  if (wave >= 4) {                        // pass B: Y rows 128..255
#pragma unroll
    for (int mt = 0; mt < 2; ++mt)
#pragma unroll
      for (int nt = 0; nt < 4; ++nt)
#pragma unroll
        for (int r = 0; r < 4; ++r)
          ybuf[((wave - 4) * 32 + mt * 16 + quad * 4 + r) * YSF + nt * 16 + col] =
              accY[mt][nt][r];
  }
  __syncthreads();                        // S5
#pragma unroll
  for (int it = 0; it < 4; ++it) {
    const int C = 128 + cb + it * 32;     // 128..255
    f32x4 v = *(const f32x4*)&ybuf[(C - 128) * YSF + n4];
    const float bias = b_oo[C];
#pragma unroll
    for (int e = 0; e < 4; ++e) v[e] += bias;
#pragma unroll
    for (int l = 0; l < 8; ++l)
      __builtin_nontemporal_store(
          v, (f32x4*)&outO[obase + (size_t)l * 524288 + C * 64 + n4]);
  }
  __syncthreads();                        // S6: ybuf free

  // ---- phase 3: agent loop (static gA/gB double buffer) ------------------
  float m_run = -3.0e38f, s_run = 0.f;
  float oacc[32];
#pragma unroll
  for (int c = 0; c < 32; ++c) oacc[c] = 0.f;

#pragma unroll 1
  for (int l = 0; l < 8; l += 2) {
    agent_step(gB, gA, l + 1, true, xo_base, xbuf, kvbuf, WKV,
               qp, oacc, m_run, s_run, t, wave, col, quad, an, ah);
    agent_step(gA, gB, l + 2, (l + 2 < 8), xo_base, xbuf, kvbuf, WKV,
               qp, oacc, m_run, s_run, t, wave, col, quad, an, ah);
  }

  // ---- phase 4: normalize -> P, out_e GEMM, 2-pass transpose + stores ----
  {
    const float inv = 1.f / s_run;
#pragma unroll
    for (int jj = 0; jj < 4; ++jj) {
      u16x8 pa;
#pragma unroll
      for (int e = 0; e < 8; ++e) pa[e] = f2bf(oacc[jj * 8 + e] * inv);
      *(u16x8*)&xbuf[an * XS + ah * 32 + jj * 8] = pa;
    }
  }
  __syncthreads();                        // E1

  f32x4 accE[2][4];
  gemm_run<2>(WOET, xbuf, wave, col, quad, accE);
  if (wave < 4) {
#pragma unroll
    for (int mt = 0; mt < 2; ++mt)
#pragma unroll
      for (int nt = 0; nt < 4; ++nt)
#pragma unroll
        for (int r = 0; r < 4; ++r)
          ybuf[(wave * 32 + mt * 16 + quad * 4 + r) * YSF + nt * 16 + col] =
              accE[mt][nt][r];
  }
  __syncthreads();                        // E2
#pragma unroll
  for (int it = 0; it < 4; ++it) {
    const int C = cb + it * 32;
    f32x4 v = *(const f32x4*)&ybuf[C * YSF + n4];
    const float bias = b_oe[C];
#pragma unroll
    for (int e = 0; e < 4; ++e) v[e] += bias;
    *(f32x4*)&out[((size_t)(bk * 256 + C)) * 64 + n4] = v;
  }
  __syncthreads();                        // E3
  if (wave >= 4) {
#pragma unroll
    for (int mt = 0; mt < 2; ++mt)
#pragma unroll
      for (int nt = 0; nt < 4; ++nt)
#pragma unroll
        for (int r = 0; r < 4; ++r)
          ybuf[((wave - 4) * 32 + mt * 16 + quad * 4 + r) * YSF + nt * 16 + col] =
              accE[mt][nt][r];
  }
  __syncthreads();                        // E4
#pragma unroll
  for (int it = 0; it < 4; ++it) {
    const int C = 128 + cb + it * 32;
    f32x4 v = *(const f32x4*)&ybuf[(C - 128) * YSF + n4];
    const float bias = b_oe[C];
#pragma unroll
    for (int e = 0; e < 4; ++e) v[e] += bias;
    *(f32x4*)&out[((size_t)(bk * 256 + C)) * 64 + n4] = v;
  }
}

// ---------------------------------------------------------------------------
extern "C" void kernel_launch(void* const* d_in, const int* in_sizes, int n_in,
                              void* d_out, int out_size, void* d_ws,
                              size_t ws_size, hipStream_t stream) {
  const float* ego    = (const float*)d_in[0];
  const float* other  = (const float*)d_in[1];
  const float* Wqkv_e = (const float*)d_in[2];
  const float* Wqkv_o = (const float*)d_in[3];
  const float* Woe    = (const float*)d_in[4];
  const float* boe    = (const float*)d_in[5];
  const float* Woo    = (const float*)d_in[6];
  const float* boo    = (const float*)d_in[7];
  float* out = (float*)d_out;

  u16* WCQ  = (u16*)d_ws;            // [512][256]
  u16* WKV  = WCQ + 512 * 256;       // [512][256]
  u16* WOET = WKV + 512 * 256;       // [256][256]

  ca_setup_fuse<<<256, 256, 0, stream>>>(Wqkv_e, Woo, WCQ);
  ca_setup_trans<<<64, 256, 0, stream>>>(Wqkv_e, Wqkv_o, Woe, WCQ, WKV, WOET);
  ca_fused<<<256, 512, 0, stream>>>(ego, other, boo, boe, WCQ, WKV, WOET, out);
}

// Round 6
// 383.956 us; speedup vs baseline: 1.5418x; 1.0002x over previous
//
#include <hip/hip_runtime.h>

// ---------------------------------------------------------------------------
// CrossAttention on MI355X (gfx950) — round 8.
//
// v7 post-mortem: fused 189 us, FETCH 230 MB (weight halving worked), but the
// out_o broadcast is a dead 512 KB/block store burst behind a barrier
// (~50k cy/CU idle), and nt stores amplified WRITE (273 vs 151 actual).
// BW utilization 26% of achievable; kernel is phase-boundary stall-bound.
//
// v8:
//  * Y kept in registers (yreg[8] = full 256-ch column/thread); agent step l
//    stores broadcast copy l (full-line, plain cached) -> drains under the
//    loop's GEMMs and x_o read stream.
//  * LDS double-buffered xbuf (x0/x1): prefetch regs written into the other
//    buffer late in the step; no more reg double-buffer, no staging burst.
//  * kvbuf stride 280 (was 264): ck/cv per-lane b128 reads spread over all
//    banks (was 8-way conflict).
//
// ws: [WCQ 512x256 bf16][WKV 512x256][WOET 256x256]  (weights only)
// ---------------------------------------------------------------------------

typedef unsigned short u16;
typedef u16  u16x8 __attribute__((ext_vector_type(8)));
typedef u16  u16x4 __attribute__((ext_vector_type(4)));
typedef __bf16 bf16x8 __attribute__((ext_vector_type(8)));
typedef float f32x4 __attribute__((ext_vector_type(4)));

#define XS   264   // LDS stride (u16) for x tiles (16B-aligned rows)
#define KVS  280   // LDS stride (u16) for kvbuf (bank-spread for row=lane reads)
#define QS   272   // LDS stride (u16) for qbuf (union with ybuf [128][68] f32)
#define YSF  68    // LDS stride (f32) for 128x64 f32 transpose buffer

__device__ __forceinline__ u16 f2bf(float f) {
  union { float f; unsigned u; } t; t.f = f;
  unsigned r = t.u + 0x7FFF + ((t.u >> 16) & 1);
  return (u16)(r >> 16);
}
__device__ __forceinline__ float bf2f(u16 x) {
  union { unsigned u; float f; } t; t.u = ((unsigned)x) << 16;
  return t.f;
}

// D[o][n] = sum_c WT[o][c]*X[n][c]; M = 8*MT*16 rows, N = 64, K = 256.
// 8 waves; WT from global (L2 weights), X from LDS [n][XS].
template <int MT>
__device__ __forceinline__ void gemm_run(const u16* __restrict__ WT,
                                         const u16* __restrict__ X,
                                         int wave, int col, int quad,
                                         f32x4 (&acc)[MT][4]) {
#pragma unroll
  for (int mt = 0; mt < MT; ++mt)
#pragma unroll
    for (int nt = 0; nt < 4; ++nt)
      acc[mt][nt] = (f32x4)(0.0f);
  for (int ks = 0; ks < 8; ++ks) {
    bf16x8 bfr[4];
#pragma unroll
    for (int nt = 0; nt < 4; ++nt)
      bfr[nt] = __builtin_bit_cast(
          bf16x8, *(const u16x8*)&X[(nt * 16 + col) * XS + ks * 32 + quad * 8]);
#pragma unroll
    for (int mt = 0; mt < MT; ++mt) {
      const int m = (wave * MT + mt) * 16 + col;
      bf16x8 afr = __builtin_bit_cast(
          bf16x8, *(const u16x8*)&WT[m * 256 + ks * 32 + quad * 8]);
#pragma unroll
      for (int nt = 0; nt < 4; ++nt)
        acc[mt][nt] = __builtin_amdgcn_mfma_f32_16x16x32_bf16(
            afr, bfr[nt], acc[mt][nt], 0, 0, 0);
    }
  }
}

// ---------------------------------------------------------------------------
// Setup: WCQ rows 0..255 = (Wv_ego @ W_out_other)^T, rows 256..511 = Wq_ego^T
// ---------------------------------------------------------------------------
__global__ void ca_setup_fuse(const float* __restrict__ Wqkv_e,
                              const float* __restrict__ Woo,
                              u16* __restrict__ WCQ) {
  const int c = blockIdx.x, o = threadIdx.x;
  __shared__ float wv[256];
  wv[o] = Wqkv_e[c * 768 + 512 + o];
  __syncthreads();
  float s = 0.f;
#pragma unroll 8
  for (int j = 0; j < 256; ++j) s += wv[j] * Woo[j * 256 + o];
  WCQ[o * 256 + c] = f2bf(s);
}

// Tiled 64x64 LDS transpose for the three weight sections.
__global__ void ca_setup_trans(const float* __restrict__ Wqkv_e,
                               const float* __restrict__ Wqkv_o,
                               const float* __restrict__ Woe,
                               u16* __restrict__ WCQ, u16* __restrict__ WKV,
                               u16* __restrict__ WOET) {
  const int bid = blockIdx.x;               // 64 blocks: job(2b)|ot(2b)|ct(2b)
  const int job = bid >> 4, ot = (bid >> 2) & 3, ct = bid & 3;
  const float* src; int stride, coff; u16* dst;
  if (job == 0)      { src = Wqkv_e; stride = 768; coff = 0;   dst = WCQ + 65536; }
  else if (job == 1) { src = Wqkv_o; stride = 768; coff = 256; dst = WKV; }
  else if (job == 2) { src = Wqkv_o; stride = 768; coff = 512; dst = WKV + 65536; }
  else               { src = Woe;    stride = 256; coff = 0;   dst = WOET; }
  __shared__ float tile[64][65];
  const int t = threadIdx.x, tc = t & 15, tr = t >> 4;   // tr in [0,16)
#pragma unroll
  for (int j = 0; j < 4; ++j) {
    const int cl = tr + j * 16;                          // local src row
    const f32x4 v =
        *(const f32x4*)&src[(ct * 64 + cl) * stride + coff + ot * 64 + tc * 4];
#pragma unroll
    for (int e = 0; e < 4; ++e) tile[cl][tc * 4 + e] = v[e];
  }
  __syncthreads();
#pragma unroll
  for (int j = 0; j < 4; ++j) {
    const int ol = tr + j * 16;                          // local dst row (o)
    u16x4 p;
#pragma unroll
    for (int e = 0; e < 4; ++e) p[e] = f2bf(tile[tc * 4 + e][ol]);
    *(u16x4*)&dst[(ot * 64 + ol) * 256 + ct * 64 + tc * 4] = p;
  }
}

// ---------------------------------------------------------------------------
// Tile staging: 64 pixels x 256 ch, f32 [c][64] global -> bf16 [n][c] LDS.
// ---------------------------------------------------------------------------
__device__ __forceinline__ void tile_load(const float* __restrict__ src, int t,
                                          f32x4 (&g)[2][4]) {
#pragma unroll
  for (int it = 0; it < 2; ++it) {
    const int id = t + it * 512;
    const int n0 = (id & 15) * 4, c0 = (id >> 4) * 4;
#pragma unroll
    for (int i = 0; i < 4; ++i)
      g[it][i] = __builtin_nontemporal_load(
          (const f32x4*)&src[(c0 + i) * 64 + n0]);
  }
}
__device__ __forceinline__ void tile_write(const f32x4 (&g)[2][4],
                                           u16* __restrict__ xbuf, int t) {
#pragma unroll
  for (int it = 0; it < 2; ++it) {
    const int id = t + it * 512;
    const int n0 = (id & 15) * 4, c0 = (id >> 4) * 4;
#pragma unroll
    for (int n = 0; n < 4; ++n) {
      u16x4 p;
#pragma unroll
      for (int i = 0; i < 4; ++i) p[i] = f2bf(g[it][i][n]);
      *(u16x4*)&xbuf[(n0 + n) * XS + c0] = p;
    }
  }
}

// ---------------------------------------------------------------------------
// One agent step (4 barriers):
//   {prefetch issue, bcast store l, K-gemm} B2 {ck} B2b {sc, V-gemm,
//    stage-write next} B3 {cv, PV} B4
// ---------------------------------------------------------------------------
__device__ __forceinline__ void agent_step(
    int L, bool pf, const float* __restrict__ xo_base,
    const u16* __restrict__ xc, u16* __restrict__ xn,
    u16* __restrict__ kvbuf, const u16* __restrict__ WKV,
    float* __restrict__ outO, size_t obase, const f32x4 (&yreg)[8],
    const u16x8 (&qp)[4], float (&oacc)[32], float& m_run, float& s_run,
    int t, int wave, int col, int quad, int an, int ah, int n4, int cb) {
  f32x4 g[2][4];
  if (pf) tile_load(xo_base + (size_t)(L + 1) * 524288, t, g);

  // broadcast copy L of Y (full 256B lines; drains under the GEMMs below)
#pragma unroll
  for (int it = 0; it < 8; ++it) {
    const int C = cb + it * 32;
    *(f32x4*)&outO[obase + (size_t)L * 524288 + C * 64 + n4] = yreg[it];
  }

  f32x4 acc[2][4];
  gemm_run<2>(WKV, xc, wave, col, quad, acc);          // K rows 0..255
#pragma unroll
  for (int mt = 0; mt < 2; ++mt) {
    const int ob = (wave * 2 + mt) * 16 + quad * 4;
#pragma unroll
    for (int nt = 0; nt < 4; ++nt) {
      u16x4 pk;
#pragma unroll
      for (int r = 0; r < 4; ++r) pk[r] = f2bf(acc[mt][nt][r]);
      *(u16x4*)&kvbuf[(nt * 16 + col) * KVS + ob] = pk;
    }
  }
  __syncthreads();                                     // B2: K ready

  u16x8 ck[4];
#pragma unroll
  for (int jj = 0; jj < 4; ++jj)
    ck[jj] = *(const u16x8*)&kvbuf[an * KVS + ah * 32 + jj * 8];
  __syncthreads();                                     // B2b: K reads done

  float sc = 0.f;
#pragma unroll
  for (int jj = 0; jj < 4; ++jj)
#pragma unroll
    for (int e = 0; e < 8; ++e) sc += bf2f(qp[jj][e]) * bf2f(ck[jj][e]);
  sc *= 0.17677669529663687f;

  gemm_run<2>(WKV + 65536, xc, wave, col, quad, acc);  // V rows 256..511
#pragma unroll
  for (int mt = 0; mt < 2; ++mt) {
    const int ob = (wave * 2 + mt) * 16 + quad * 4;
#pragma unroll
    for (int nt = 0; nt < 4; ++nt) {
      u16x4 pv;
#pragma unroll
      for (int r = 0; r < 4; ++r) pv[r] = f2bf(acc[mt][nt][r]);
      *(u16x4*)&kvbuf[(nt * 16 + col) * KVS + ob] = pv;
    }
  }
  if (pf) tile_write(g, xn, t);                        // stage next agent

  const float mnew = fmaxf(m_run, sc);
  const float p = __expf(sc - mnew);
  const float al = __expf(m_run - mnew);
  s_run = s_run * al + p;
  m_run = mnew;
  __syncthreads();                                     // B3: V + next x ready

  u16x8 cv[4];
#pragma unroll
  for (int jj = 0; jj < 4; ++jj)
    cv[jj] = *(const u16x8*)&kvbuf[an * KVS + ah * 32 + jj * 8];
#pragma unroll
  for (int jj = 0; jj < 4; ++jj)
#pragma unroll
    for (int e = 0; e < 8; ++e)
      oacc[jj * 8 + e] = oacc[jj * 8 + e] * al + p * bf2f(cv[jj][e]);
  __syncthreads();                                     // B4: V reads done
}

// ---------------------------------------------------------------------------
// Fused kernel: grid = 256 (bk), 512 thr (8 waves), 1 block/CU, LDS 138 KB.
// ---------------------------------------------------------------------------
__global__ __launch_bounds__(512, 2) void ca_fused(
    const float* __restrict__ ego, const float* __restrict__ other,
    const float* __restrict__ b_oo, const float* __restrict__ b_oe,
    const u16* __restrict__ WCQ, const u16* __restrict__ WKV,
    const u16* __restrict__ WOET, float* __restrict__ out) {
  // XCD swizzle (bijective: 256 % 8 == 0): contiguous bk chunk per XCD.
  const int g = blockIdx.x;
  const int bk = (g & 7) * 32 + (g >> 3);
  const int b = bk >> 5, kk = bk & 31;
  const int t = threadIdx.x;
  const int lane = t & 63, wave = t >> 6;
  const int col = lane & 15, quad = lane >> 4;
  const int an = t & 63, ah = t >> 6;     // attention: pixel 0..63, head 0..7
  const int n4 = (t & 15) * 4, cb = t >> 4;   // transpose/store lanes

  __shared__ u16 x0[64 * XS];                          // 33792 B
  __shared__ u16 x1[64 * XS];                          // 33792 B
  __shared__ u16 kvbuf[64 * KVS];                      // 35840 B
  __shared__ __align__(16) char ubuf[64 * QS * 2];     // 34816 B (qbuf|ybuf)
  u16*   qbuf = (u16*)ubuf;                            // [64][QS]
  float* ybuf = (float*)ubuf;                          // [128][YSF]

  const float* xe_src  = ego + (size_t)bk * 16384;
  const float* xo_base = other + (size_t)(b * 256 + kk) * 16384;
  float* outO = out + 4194304;
  const size_t obase = (size_t)(b * 256 + kk) * 16384;

  // ---- phase 0: stage x_e ------------------------------------------------
  {
    f32x4 ge[2][4];
    tile_load(xe_src, t, ge);
    tile_write(ge, x0, t);
  }
  __syncthreads();                        // P1: x0 = x_e ready

  f32x4 g0[2][4];
  tile_load(xo_base, t, g0);              // prefetch agent 0 (under prologue)

  // ---- phase 1: Y-gemm + Q-gemm (each M=256, N=64) -----------------------
  f32x4 accY[2][4], accQ[2][4];
  gemm_run<2>(WCQ, x0, wave, col, quad, accY);           // fused rows
  gemm_run<2>(WCQ + 65536, x0, wave, col, quad, accQ);   // q rows
#pragma unroll
  for (int mt = 0; mt < 2; ++mt) {        // Q -> qbuf [n][o]
    const int ob = (wave * 2 + mt) * 16 + quad * 4;
#pragma unroll
    for (int nt = 0; nt < 4; ++nt) {
      u16x4 pq;
#pragma unroll
      for (int r = 0; r < 4; ++r) pq[r] = f2bf(accQ[mt][nt][r]);
      *(u16x4*)&qbuf[(nt * 16 + col) * QS + ob] = pq;
    }
  }
  __syncthreads();                        // P2: qbuf ready, all x0 reads done

  u16x8 qp[4];
#pragma unroll
  for (int jj = 0; jj < 4; ++jj)
    qp[jj] = *(const u16x8*)&qbuf[an * QS + ah * 32 + jj * 8];
  tile_write(g0, x0, t);                  // agent 0 overwrites x_e
  __syncthreads();                        // P3: q reads done, ubuf -> ybuf

  // ---- phase 2: Y transpose -> yreg (+bias), 2 passes --------------------
  f32x4 yreg[8];
  if (wave < 4) {                         // pass A: Y rows 0..127
#pragma unroll
    for (int mt = 0; mt < 2; ++mt)
#pragma unroll
      for (int nt = 0; nt < 4; ++nt)
#pragma unroll
        for (int r = 0; r < 4; ++r)
          ybuf[(wave * 32 + mt * 16 + quad * 4 + r) * YSF + nt * 16 + col] =
              accY[mt][nt][r];
  }
  __syncthreads();                        // P4
#pragma unroll
  for (int it = 0; it < 4; ++it) {
    const int C = cb + it * 32;           // 0..127
    f32x4 v = *(const f32x4*)&ybuf[C * YSF + n4];
    const float bias = b_oo[C];
#pragma unroll
    for (int e = 0; e < 4; ++e) v[e] += bias;
    yreg[it] = v;
  }
  __syncthreads();                        // P5
  if (wave >= 4) {                        // pass B: Y rows 128..255
#pragma unroll
    for (int mt = 0; mt < 2; ++mt)
#pragma unroll
      for (int nt = 0; nt < 4; ++nt)
#pragma unroll
        for (int r = 0; r < 4; ++r)
          ybuf[((wave - 4) * 32 + mt * 16 + quad * 4 + r) * YSF + nt * 16 + col] =
              accY[mt][nt][r];
  }
  __syncthreads();                        // P6
#pragma unroll
  for (int it = 0; it < 4; ++it) {
    const int C = 128 + cb + it * 32;     // 128..255
    f32x4 v = *(const f32x4*)&ybuf[(C - 128) * YSF + n4];
    const float bias = b_oo[C];
#pragma unroll
    for (int e = 0; e < 4; ++e) v[e] += bias;
    yreg[4 + it] = v;
  }
  __syncthreads();                        // P7: ybuf reads done

  // ---- phase 3: agent loop (LDS-double-buffered staging) -----------------
  float m_run = -3.0e38f, s_run = 0.f;
  float oacc[32];
#pragma unroll
  for (int c = 0; c < 32; ++c) oacc[c] = 0.f;

#pragma unroll 1
  for (int l = 0; l < 8; l += 2) {
    agent_step(l, true, xo_base, x0, x1, kvbuf, WKV, outO, obase,
               yreg, qp, oacc, m_run, s_run,
               t, wave, col, quad, an, ah, n4, cb);
    agent_step(l + 1, l + 1 < 7, xo_base, x1, x0, kvbuf, WKV, outO, obase,
               yreg, qp, oacc, m_run, s_run,
               t, wave, col, quad, an, ah, n4, cb);
  }

  // ---- phase 4: normalize -> P, out_e GEMM, 2-pass transpose + stores ----
  {
    const float inv = 1.f / s_run;
#pragma unroll
    for (int jj = 0; jj < 4; ++jj) {
      u16x8 pa;
#pragma unroll
      for (int e = 0; e < 8; ++e) pa[e] = f2bf(oacc[jj * 8 + e] * inv);
      *(u16x8*)&x0[an * XS + ah * 32 + jj * 8] = pa;
    }
  }
  __syncthreads();                        // E1

  f32x4 accE[2][4];
  gemm_run<2>(WOET, x0, wave, col, quad, accE);
  if (wave < 4) {
#pragma unroll
    for (int mt = 0; mt < 2; ++mt)
#pragma unroll
      for (int nt = 0; nt < 4; ++nt)
#pragma unroll
        for (int r = 0; r < 4; ++r)
          ybuf[(wave * 32 + mt * 16 + quad * 4 + r) * YSF + nt * 16 + col] =
              accE[mt][nt][r];
  }
  __syncthreads();                        // E2
#pragma unroll
  for (int it = 0; it < 4; ++it) {
    const int C = cb + it * 32;
    f32x4 v = *(const f32x4*)&ybuf[C * YSF + n4];
    const float bias = b_oe[C];
#pragma unroll
    for (int e = 0; e < 4; ++e) v[e] += bias;
    *(f32x4*)&out[((size_t)(bk * 256 + C)) * 64 + n4] = v;
  }
  __syncthreads();                        // E3
  if (wave >= 4) {
#pragma unroll
    for (int mt = 0; mt < 2; ++mt)
#pragma unroll
      for (int nt = 0; nt < 4; ++nt)
#pragma unroll
        for (int r = 0; r < 4; ++r)
          ybuf[((wave - 4) * 32 + mt * 16 + quad * 4 + r) * YSF + nt * 16 + col] =
              accE[mt][nt][r];
  }
  __syncthreads();                        // E4
#pragma unroll
  for (int it = 0; it < 4; ++it) {
    const int C = 128 + cb + it * 32;
    f32x4 v = *(const f32x4*)&ybuf[(C - 128) * YSF + n4];
    const float bias = b_oe[C];
#pragma unroll
    for (int e = 0; e < 4; ++e) v[e] += bias;
    *(f32x4*)&out[((size_t)(bk * 256 + C)) * 64 + n4] = v;
  }
}

// ---------------------------------------------------------------------------
extern "C" void kernel_launch(void* const* d_in, const int* in_sizes, int n_in,
                              void* d_out, int out_size, void* d_ws,
                              size_t ws_size, hipStream_t stream) {
  const float* ego    = (const float*)d_in[0];
  const float* other  = (const float*)d_in[1];
  const float* Wqkv_e = (const float*)d_in[2];
  const float* Wqkv_o = (const float*)d_in[3];
  const float* Woe    = (const float*)d_in[4];
  const float* boe    = (const float*)d_in[5];
  const float* Woo    = (const float*)d_in[6];
  const float* boo    = (const float*)d_in[7];
  float* out = (float*)d_out;

  u16* WCQ  = (u16*)d_ws;            // [512][256]
  u16* WKV  = WCQ + 512 * 256;       // [512][256]
  u16* WOET = WKV + 512 * 256;       // [256][256]

  ca_setup_fuse<<<256, 256, 0, stream>>>(Wqkv_e, Woo, WCQ);
  ca_setup_trans<<<64, 256, 0, stream>>>(Wqkv_e, Wqkv_o, Woe, WCQ, WKV, WOET);
  ca_fused<<<256, 512, 0, stream>>>(ego, other, boo, boe, WCQ, WKV, WOET, out);
}